// Round 11
// baseline (135.479 us; speedup 1.0000x reference)
//
#include <hip/hip_runtime.h>
#include <hip/hip_bf16.h>

typedef float fvec4 __attribute__((ext_vector_type(4)));
typedef unsigned short ushort_t;
typedef unsigned int uint_t;

#define NBLK 256
#define TPB  1024
#define NG   16             // waves per block
#define CN   512            // nodes per chunk

// ---- LDS layout ----
// floats: [WT 12032][BIAS 1024][XSH 8192][IDX 2048 ints][CNT 4 ints]
// then bf16 tables (ushort) at byte 93200 (8B aligned).
#define WT0    0            // 11 x 256
#define WT1    2816         // 12 x 256
#define WT2    5888
#define WT3    8960
#define BIASF  12032        // 4 x 256
#define XSHF   13056        // CN*16 floats
#define IDXI   21248        // 4*CN ints (at float index)
#define CNTI   23296        // 4 ints
#define SMEM_FLOATS 23300
#define TABU   46600        // ushort index of table base (byte 93200)

// table offsets (ushort units, relative to TABU) — type-0 padded to stride 88,
// bases chosen so (base - first_col) % 4 == 0 => 8B-aligned b64 gathers.
#define O_E0_2 0            // 96 x 88 = 8448
#define O_E0_3 8450         // 8  x 88 -> 9154   (8450-86  = 8364 %4==0)
#define O_E0_5 9155         // 2  x 88 -> 9331   (9155-171 = 8984 %4==0)
#define O_E1_2 9332         // 4  x 128
#define O_E1_3 9844         // 22 x 128          (9844-128 = 9716 %4==0)
#define O_E2_0 12660        // 6  x 256
#define O_E3_0 14196        // 15 x 128
#define O_E3_1 16116        // 96 x 128          (16116-128 = 15988 %4==0)
#define NTABU  28404
#define SMEM_BYTES (93200 + NTABU * 2)   // 150008 B < 160 KiB

extern __shared__ float smem[];

__device__ __forceinline__ ushort_t f2bf(float v) {
    __hip_bfloat16 h = __float2bfloat16(v);
    return *reinterpret_cast<ushort_t*>(&h);
}
__device__ __forceinline__ float bf2f(ushort_t u) {
    return __uint_as_float(((uint_t)u) << 16);
}

#define FMA4(K, XV)                                   \
    acc.x = fmaf(w4[K].x, (XV), acc.x);               \
    acc.y = fmaf(w4[K].y, (XV), acc.y);               \
    acc.z = fmaf(w4[K].z, (XV), acc.z);               \
    acc.w = fmaf(w4[K].w, (XV), acc.w);

__global__ __launch_bounds__(TPB, 1)
void node_enc_kernel(const float* __restrict__ x,
                     const int* __restrict__ node_types,
                     const float* __restrict__ W0, const float* __restrict__ b0,
                     const float* __restrict__ E0_2, const float* __restrict__ E0_3,
                     const float* __restrict__ E0_5,
                     const float* __restrict__ W1, const float* __restrict__ b1,
                     const float* __restrict__ E1_2, const float* __restrict__ E1_3,
                     const float* __restrict__ W2, const float* __restrict__ b2,
                     const float* __restrict__ E2_0,
                     const float* __restrict__ W3, const float* __restrict__ b3,
                     const float* __restrict__ E3_0, const float* __restrict__ E3_1,
                     float* __restrict__ out, int n_nodes)
{
    const int tid = threadIdx.x;
    const int q   = tid & 63;    // lane: owns output cols 4q..4q+3
    const int h   = tid >> 6;    // wave index within block (0..15)

    ushort_t* const tab = reinterpret_cast<ushort_t*>(smem) + TABU;

    // ---------- prologue: weights (transposed, fp32) + tables (bf16) -> LDS ----------
    auto copy_wt = [&](const float* __restrict__ W, const float* __restrict__ b,
                       int wt, int t, int NW) {
        const int n = 256 * NW;
        for (int i = tid; i < n; i += TPB) {
            const int col = i / NW, k = i - col * NW;
            smem[wt + k * 256 + col] = W[i];
        }
        for (int i = tid; i < 256; i += TPB) smem[BIASF + t * 256 + i] = b[i];
    };
    copy_wt(W0, b0, WT0, 0, 11);
    copy_wt(W1, b1, WT1, 1, 12);
    copy_wt(W2, b2, WT2, 2, 12);
    copy_wt(W3, b3, WT3, 3, 12);

    auto copy_tab_bf = [&](const float* __restrict__ src, int dst, int n) {
        for (int i = tid; i < n; i += TPB) tab[dst + i] = f2bf(src[i]);
    };
    auto copy_tab_pad_bf = [&](const float* __restrict__ src, int dst, int rows, int cols) {
        const int n = rows * cols;
        for (int i = tid; i < n; i += TPB) {
            const int r = i / cols, c2 = i - r * cols;
            tab[dst + r * 88 + c2] = f2bf(src[i]);
        }
    };
    copy_tab_pad_bf(E0_2, O_E0_2, 96, 86);
    copy_tab_pad_bf(E0_3, O_E0_3, 8, 85);
    copy_tab_pad_bf(E0_5, O_E0_5, 2, 85);
    copy_tab_bf(E1_2, O_E1_2, 512);
    copy_tab_bf(E1_3, O_E1_3, 2816);
    copy_tab_bf(E2_0, O_E2_0, 1536);
    copy_tab_bf(E3_0, O_E3_0, 1920);
    copy_tab_bf(E3_1, O_E3_1, 12288);

    // ---------- chunk range for this block ----------
    const int nch = (n_nodes + CN - 1) / CN;
    const int c0  = (int)(((long long)blockIdx.x * nch) / NBLK);
    const int c1  = (int)(((long long)(blockIdx.x + 1) * nch) / NBLK);

    int* const idx_m = reinterpret_cast<int*>(&smem[IDXI]);
    int* const cnt_m = reinterpret_cast<int*>(&smem[CNTI]);
    const int* idx_ro = idx_m;
    const int* cnt_ro = cnt_m;

    // ---------- staging helpers (reg-staged, issue-early / write-late) ----------
    auto stage_issue = [&](int c, fvec4& r0, fvec4& r1,
                           float& rs, int& ty, int& nv, int& total, int& cnn) {
        const long long cb = (long long)c * CN;
        cnn   = min(CN, (int)(n_nodes - cb));
        total = cnn * 14;
        nv    = total >> 2;            // max 1792 (< 2*TPB)
        const fvec4* vsrc = reinterpret_cast<const fvec4*>(x + cb * 14);
        if (tid < nv)          r0 = __builtin_nontemporal_load(vsrc + tid);
        if (tid + TPB < nv)    r1 = __builtin_nontemporal_load(vsrc + tid + TPB);
        const int sf = (nv << 2) + tid;
        if (sf < total) rs = x[cb * 14 + sf];
        if (tid < cnn)  ty = node_types[cb + tid];
    };
    auto stage_write = [&](const fvec4& r0, const fvec4& r1,
                           float rs, int nv, int total) {
        auto wr1 = [&](int i, const fvec4& v) {
            const int f = i << 2;
            int node = f / 14, col = f - node * 14;
            #pragma unroll
            for (int j = 0; j < 4; ++j) {
                smem[XSHF + node * 16 + col] = v[j];
                if (++col == 14) { col = 0; ++node; }
            }
        };
        if (tid < nv)        wr1(tid, r0);
        if (tid + TPB < nv)  wr1(tid + TPB, r1);
        const int sf = (nv << 2) + tid;
        if (sf < total) { const int node = sf / 14, col = sf - node * 14; smem[XSHF + node * 16 + col] = rs; }
    };

    // ---------- compute one chunk: 4 sequential type-specialized loops ----------
    auto do_chunk = [&](int c) {
        const long long cb = (long long)c * CN;

        // ===== type 0 =====
        {
            const int m = cnt_ro[0];
            float4 w4[11];
            #pragma unroll
            for (int k = 0; k < 11; ++k)
                w4[k] = *reinterpret_cast<const float4*>(&smem[WT0 + k * 256 + 4 * q]);
            const float4 bias = *reinterpret_cast<const float4*>(&smem[BIASF + 0 * 256 + 4 * q]);
            int scv, ebase;
            const bool fb = (q == 21) || (q == 42);
            if (q <= 21)      { scv = 2; ebase = O_E0_2 + 4 * q; }
            else if (q <= 42) { scv = 3; ebase = (O_E0_3 - 86) + 4 * q; }
            else              { scv = 5; ebase = (O_E0_5 - 171) + 4 * q; }
            for (int g = h; g < m; g += NG) {
                const int nl = idx_ro[0 * CN + g];
                const float* xr = &smem[XSHF + nl * 16];
                const float4 ra = *reinterpret_cast<const float4*>(xr);
                const float4 rb = *reinterpret_cast<const float4*>(xr + 4);
                const float4 rc = *reinterpret_cast<const float4*>(xr + 8);
                const float2 rd = *reinterpret_cast<const float2*>(xr + 12);
                float4 acc = bias;
                FMA4(0,  ra.x) FMA4(1,  ra.y) FMA4(2,  rb.x) FMA4(3,  rb.z)
                FMA4(4,  rb.w) FMA4(5,  rc.x) FMA4(6,  rc.y) FMA4(7,  rc.z)
                FMA4(8,  rc.w) FMA4(9,  rd.x) FMA4(10, rd.y)
                float4 ev;
                if (fb) {
                    if (q == 21) {
                        const int c2 = (int)xr[2], c3 = (int)xr[3];
                        ev.x = bf2f(tab[O_E0_2 + c2 * 88 + 84]);
                        ev.y = bf2f(tab[O_E0_2 + c2 * 88 + 85]);
                        ev.z = bf2f(tab[O_E0_3 + c3 * 88 + 0]);
                        ev.w = bf2f(tab[O_E0_3 + c3 * 88 + 1]);
                    } else {
                        const int c3 = (int)xr[3], c5 = (int)xr[5];
                        ev.x = bf2f(tab[O_E0_3 + c3 * 88 + 82]);
                        ev.y = bf2f(tab[O_E0_3 + c3 * 88 + 83]);
                        ev.z = bf2f(tab[O_E0_3 + c3 * 88 + 84]);
                        ev.w = bf2f(tab[O_E0_5 + c5 * 88 + 0]);
                    }
                } else {
                    const int code = (int)xr[scv];
                    const uint2 u = *reinterpret_cast<const uint2*>(&tab[ebase + code * 88]);
                    ev.x = __uint_as_float(u.x << 16);
                    ev.y = __uint_as_float(u.x & 0xffff0000u);
                    ev.z = __uint_as_float(u.y << 16);
                    ev.w = __uint_as_float(u.y & 0xffff0000u);
                }
                acc.x += ev.x; acc.y += ev.y; acc.z += ev.z; acc.w += ev.w;
                *reinterpret_cast<float4*>(&out[(cb + nl) * 256 + 4 * q]) = acc;
            }
        }

        // ===== type 1 =====
        {
            const int m = cnt_ro[1];
            float4 w4[12];
            #pragma unroll
            for (int k = 0; k < 12; ++k)
                w4[k] = *reinterpret_cast<const float4*>(&smem[WT1 + k * 256 + 4 * q]);
            const float4 bias = *reinterpret_cast<const float4*>(&smem[BIASF + 1 * 256 + 4 * q]);
            const int scv   = (q < 32) ? 2 : 3;
            const int ebase = ((q < 32) ? O_E1_2 : (O_E1_3 - 128)) + 4 * q;
            for (int g = h; g < m; g += NG) {
                const int nl = idx_ro[1 * CN + g];
                const float* xr = &smem[XSHF + nl * 16];
                const float4 ra = *reinterpret_cast<const float4*>(xr);
                const float4 rb = *reinterpret_cast<const float4*>(xr + 4);
                const float4 rc = *reinterpret_cast<const float4*>(xr + 8);
                const float2 rd = *reinterpret_cast<const float2*>(xr + 12);
                float4 acc = bias;
                FMA4(0,  ra.x) FMA4(1,  ra.y) FMA4(2,  rb.x) FMA4(3,  rb.y)
                FMA4(4,  rb.z) FMA4(5,  rb.w) FMA4(6,  rc.x) FMA4(7,  rc.y)
                FMA4(8,  rc.z) FMA4(9,  rc.w) FMA4(10, rd.x) FMA4(11, rd.y)
                const int code = (int)xr[scv];
                const uint2 u = *reinterpret_cast<const uint2*>(&tab[ebase + code * 128]);
                float4 ev;
                ev.x = __uint_as_float(u.x << 16);
                ev.y = __uint_as_float(u.x & 0xffff0000u);
                ev.z = __uint_as_float(u.y << 16);
                ev.w = __uint_as_float(u.y & 0xffff0000u);
                acc.x += ev.x; acc.y += ev.y; acc.z += ev.z; acc.w += ev.w;
                *reinterpret_cast<float4*>(&out[(cb + nl) * 256 + 4 * q]) = acc;
            }
        }

        // ===== type 2 =====
        {
            const int m = cnt_ro[2];
            float4 w4[12];
            #pragma unroll
            for (int k = 0; k < 12; ++k)
                w4[k] = *reinterpret_cast<const float4*>(&smem[WT2 + k * 256 + 4 * q]);
            const float4 bias = *reinterpret_cast<const float4*>(&smem[BIASF + 2 * 256 + 4 * q]);
            const int ebase = O_E2_0 + 4 * q;
            for (int g = h; g < m; g += NG) {
                const int nl = idx_ro[2 * CN + g];
                const float* xr = &smem[XSHF + nl * 16];
                const float4 ra = *reinterpret_cast<const float4*>(xr);
                const float4 rb = *reinterpret_cast<const float4*>(xr + 4);
                const float4 rc = *reinterpret_cast<const float4*>(xr + 8);
                const float2 rd = *reinterpret_cast<const float2*>(xr + 12);
                float4 acc = bias;
                FMA4(0,  ra.y) FMA4(1,  ra.z) FMA4(2,  rb.x) FMA4(3,  rb.y)
                FMA4(4,  rb.z) FMA4(5,  rb.w) FMA4(6,  rc.x) FMA4(7,  rc.y)
                FMA4(8,  rc.z) FMA4(9,  rc.w) FMA4(10, rd.x) FMA4(11, rd.y)
                const int code = (int)xr[0];
                const uint2 u = *reinterpret_cast<const uint2*>(&tab[ebase + code * 256]);
                float4 ev;
                ev.x = __uint_as_float(u.x << 16);
                ev.y = __uint_as_float(u.x & 0xffff0000u);
                ev.z = __uint_as_float(u.y << 16);
                ev.w = __uint_as_float(u.y & 0xffff0000u);
                acc.x += ev.x; acc.y += ev.y; acc.z += ev.z; acc.w += ev.w;
                *reinterpret_cast<float4*>(&out[(cb + nl) * 256 + 4 * q]) = acc;
            }
        }

        // ===== type 3 =====
        {
            const int m = cnt_ro[3];
            float4 w4[12];
            #pragma unroll
            for (int k = 0; k < 12; ++k)
                w4[k] = *reinterpret_cast<const float4*>(&smem[WT3 + k * 256 + 4 * q]);
            const float4 bias = *reinterpret_cast<const float4*>(&smem[BIASF + 3 * 256 + 4 * q]);
            const int scv   = (q < 32) ? 0 : 1;
            const int ebase = ((q < 32) ? O_E3_0 : (O_E3_1 - 128)) + 4 * q;
            for (int g = h; g < m; g += NG) {
                const int nl = idx_ro[3 * CN + g];
                const float* xr = &smem[XSHF + nl * 16];
                const float4 ra = *reinterpret_cast<const float4*>(xr);
                const float4 rb = *reinterpret_cast<const float4*>(xr + 4);
                const float4 rc = *reinterpret_cast<const float4*>(xr + 8);
                const float2 rd = *reinterpret_cast<const float2*>(xr + 12);
                float4 acc = bias;
                FMA4(0,  ra.z) FMA4(1,  ra.w) FMA4(2,  rb.x) FMA4(3,  rb.y)
                FMA4(4,  rb.z) FMA4(5,  rb.w) FMA4(6,  rc.x) FMA4(7,  rc.y)
                FMA4(8,  rc.z) FMA4(9,  rc.w) FMA4(10, rd.x) FMA4(11, rd.y)
                const int code = (int)xr[scv];
                const uint2 u = *reinterpret_cast<const uint2*>(&tab[ebase + code * 128]);
                float4 ev;
                ev.x = __uint_as_float(u.x << 16);
                ev.y = __uint_as_float(u.x & 0xffff0000u);
                ev.z = __uint_as_float(u.y << 16);
                ev.w = __uint_as_float(u.y & 0xffff0000u);
                acc.x += ev.x; acc.y += ev.y; acc.z += ev.z; acc.w += ev.w;
                *reinterpret_cast<float4*>(&out[(cb + nl) * 256 + 4 * q]) = acc;
            }
        }
    };

    // ---------- prologue: stage + bucket first chunk ----------
    {
        fvec4 r0, r1; float rs = 0.f; int ty = 0, nv = 0, total = 0, cnn = 0;
        if (c0 < c1) {
            stage_issue(c0, r0, r1, rs, ty, nv, total, cnn);
            stage_write(r0, r1, rs, nv, total);
            if (tid < 4) cnt_m[tid] = 0;
        }
        __syncthreads();
        if (c0 < c1 && tid < cnn) {
            const int p = atomicAdd(&cnt_m[ty], 1);
            idx_m[ty * CN + p] = tid;
        }
        __syncthreads();
    }

    // ---------- main loop: compute chunk c while staging+bucketing c+1 ----------
    for (int c = c0; c < c1; ++c) {
        fvec4 r0, r1; float rs = 0.f; int ty = 0, nv = 0, total = 0, cnn = 0;
        const bool hasnext = (c + 1 < c1);
        if (hasnext) stage_issue(c + 1, r0, r1, rs, ty, nv, total, cnn);
        do_chunk(c);
        __syncthreads();                    // all reads of xsh/idx done
        if (hasnext) {
            stage_write(r0, r1, rs, nv, total);
            if (tid < 4) cnt_m[tid] = 0;
        }
        __syncthreads();                    // xsh written, counters zeroed
        if (hasnext && tid < cnn) {
            const int p = atomicAdd(&cnt_m[ty], 1);
            idx_m[ty * CN + p] = tid;
        }
        __syncthreads();                    // lists ready for next iteration
    }
}

extern "C" void kernel_launch(void* const* d_in, const int* in_sizes, int n_in,
                              void* d_out, int out_size, void* d_ws, size_t ws_size,
                              hipStream_t stream) {
    // setup_inputs() dict order:
    //  0:x  1:node_types  2:W0 3:b0 4:E0_2 5:E0_3 6:E0_5
    //  7:W1 8:b1 9:E1_2 10:E1_3  11:W2 12:b2 13:E2_0  14:W3 15:b3 16:E3_0 17:E3_1
    const float* xp   = (const float*)d_in[0];
    const int*   ntp  = (const int*)d_in[1];
    const float* W0 = (const float*)d_in[2];
    const float* b0 = (const float*)d_in[3];
    const float* E0_2 = (const float*)d_in[4];
    const float* E0_3 = (const float*)d_in[5];
    const float* E0_5 = (const float*)d_in[6];
    const float* W1 = (const float*)d_in[7];
    const float* b1 = (const float*)d_in[8];
    const float* E1_2 = (const float*)d_in[9];
    const float* E1_3 = (const float*)d_in[10];
    const float* W2 = (const float*)d_in[11];
    const float* b2 = (const float*)d_in[12];
    const float* E2_0 = (const float*)d_in[13];
    const float* W3 = (const float*)d_in[14];
    const float* b3 = (const float*)d_in[15];
    const float* E3_0 = (const float*)d_in[16];
    const float* E3_1 = (const float*)d_in[17];
    float* outp = (float*)d_out;

    const int n_nodes = in_sizes[1];

    (void)hipFuncSetAttribute(reinterpret_cast<const void*>(node_enc_kernel),
                              hipFuncAttributeMaxDynamicSharedMemorySize, SMEM_BYTES);

    node_enc_kernel<<<NBLK, TPB, SMEM_BYTES, stream>>>(
        xp, ntp, W0, b0, E0_2, E0_3, E0_5, W1, b1, E1_2, E1_3,
        W2, b2, E2_0, W3, b3, E3_0, E3_1, outp, n_nodes);
}